// Round 14
// baseline (5378.691 us; speedup 1.0000x reference)
//
#include <hip/hip_runtime.h>

// SpikeFFN: out = spike(LIF(x @ W1^T)) @ W2^T ; T=4 B=8 N=1024 C=512, fp32.
//
// HARD CONSTRAINT (r8): GEMM1 = single full-K ascending serial FMA chain per
// output in fp32 (np reference arithmetic); v_fma_f32 == CPU vfmadd.
// Tiling/load order free; per-output chain order is not.
//
// r13 post-mortem: B via readfirstlane-uniform pointer -> SMEM s_load; SMEM
// returns are OUT-OF-ORDER on gfx9 => only lgkmcnt(0) waits, and DS shares
// lgkm => every k-group drains both pipes (~34% VALU idle, VALUBusy 66%).
// r14: B -> VMEM (per-lane wave-uniform address, global_load_dwordx4 x4,
// broadcast-coalesced) with explicit even/odd register double-buffer.
// VMEM is in-order (fine vmcnt waits); lgkm left to DS alone. B prefetch
// runs along ascending gk continuously across tiles (B is tile-independent).

typedef _Float16 half8  __attribute__((ext_vector_type(8)));
typedef _Float16 half4v __attribute__((ext_vector_type(4)));
typedef float    f32x4  __attribute__((ext_vector_type(4)));
typedef unsigned short ushort8 __attribute__((ext_vector_type(8)));

constexpr int TT   = 4;
constexpr int BB   = 8;
constexpr int NN   = 1024;
constexpr int CC   = 512;                 // Cin == Cout
constexpr int MROW = BB * NN;             // 8192 rows per timestep
constexpr int MTOT = TT * MROW;           // 32768 rows total
constexpr int BNC  = MROW * CC;           // per-timestep elems
constexpr int LDK  = 40;                  // fp16 LDS stride (gemm2)
constexpr int LTA  = 260;                 // fp32 LDS row stride (256+4 pad)

// --------------------------- W1 -> Wt[k][o] transpose ----------------------
__global__ __launch_bounds__(256)
void transpose_w(const float* __restrict__ W, float* __restrict__ Wt) {
    __shared__ float T[64][65];
    const int tid = threadIdx.x;
    const int bo  = blockIdx.x * 64;   // o tile
    const int bk  = blockIdx.y * 64;   // k tile
#pragma unroll
    for (int j = 0; j < 16; ++j) {
        int id = tid + 256 * j;
        int r = id >> 6, c = id & 63;              // r: o, c: k
        T[r][c] = W[(size_t)(bo + r) * CC + bk + c];
    }
    __syncthreads();
#pragma unroll
    for (int j = 0; j < 16; ++j) {
        int id = tid + 256 * j;
        int r = id >> 6, c = id & 63;              // r: k, c: o
        Wt[(size_t)(bk + r) * CC + bo + c] = T[c][r];
    }
}

// ---------- GEMM1: single full-K ascending serial FMA chain (fp32) ---------
// 256x128 block tile, 512 threads (8 waves x 16 cols), 4x16 outputs/thread.
// A in dbuf LDS (contiguous-b128 lane reads, lgkm/DS only);
// B from Wt via VMEM broadcast loads, even/odd register double-buffer.
__global__ __launch_bounds__(512, 4)
void gemm1_vmem(const float* __restrict__ X, const float* __restrict__ Wt,
                float* __restrict__ H) {
#pragma clang fp contract(off)
    __shared__ float At[2][32][LTA];   // 66.5 KB

    const int tid  = threadIdx.x;
    const int lane = tid & 63;
    const int wid  = tid >> 6;                     // uniform-per-wave, VGPR path
    const int RM   = blockIdx.x * 256;
    const int CN   = blockIdx.y * 128 + wid * 16;  // wave col base
    const float* wcol = Wt + CN;                   // Wt[gk][CN..CN+15]

    const int srow = tid >> 1;           // staging row 0..255
    const int sk16 = (tid & 1) * 16;     // staging k base (0 or 16)

    float acc[4][16] = {};               // ONE accumulator per output
    f32x4 rx[4];                         // A prefetch
    f32x4 be[4], bo[4];                  // B even/odd k register dbuf

    // prologue: stage A tile 0; preload B for gk=0
#pragma unroll
    for (int q = 0; q < 4; ++q)
        rx[q] = *(const f32x4*)&X[(size_t)(RM + srow) * CC + sk16 + q * 4];
#pragma unroll
    for (int q = 0; q < 4; ++q)
#pragma unroll
        for (int e = 0; e < 4; ++e)
            At[0][sk16 + q * 4 + e][srow] = rx[q][e];
#pragma unroll
    for (int q = 0; q < 4; ++q)
        be[q] = *(const f32x4*)&wcol[q * 4];       // gk = 0
    __syncthreads();

    for (int kt = 0; kt < 16; ++kt) {
        const int cur = kt & 1;
        // issue A loads for tile kt+1 (land under this tile's FMAs)
        if (kt < 15) {
            int kk = (kt + 1) * 32;
#pragma unroll
            for (int q = 0; q < 4; ++q)
                rx[q] = *(const f32x4*)&X[(size_t)(RM + srow) * CC + kk + sk16 + q * 4];
        }
        // FMA phase: strict ascending k; B prefetched one k ahead via VMEM
#pragma unroll
        for (int k = 0; k < 32; k += 2) {
            const int gk = kt * 32 + k;
            // prefetch B for gk+1 (odd)
            const float* p1 = &wcol[(size_t)(gk + 1 < 512 ? gk + 1 : 511) * CC];
#pragma unroll
            for (int q = 0; q < 4; ++q) bo[q] = *(const f32x4*)&p1[q * 4];
            // FMA k (even) with be
            {
                f32x4 a = *(const f32x4*)&At[cur][k][lane * 4];
#pragma unroll
                for (int i = 0; i < 4; ++i)
#pragma unroll
                    for (int q = 0; q < 4; ++q)
#pragma unroll
                        for (int e = 0; e < 4; ++e)
                            acc[i][q * 4 + e] = __builtin_fmaf(a[i], be[q][e], acc[i][q * 4 + e]);
            }
            // prefetch B for gk+2 (next even)
            const float* p2 = &wcol[(size_t)(gk + 2 < 512 ? gk + 2 : 511) * CC];
#pragma unroll
            for (int q = 0; q < 4; ++q) be[q] = *(const f32x4*)&p2[q * 4];
            // FMA k+1 (odd) with bo
            {
                f32x4 a = *(const f32x4*)&At[cur][k + 1][lane * 4];
#pragma unroll
                for (int i = 0; i < 4; ++i)
#pragma unroll
                    for (int q = 0; q < 4; ++q)
#pragma unroll
                        for (int e = 0; e < 4; ++e)
                            acc[i][q * 4 + e] = __builtin_fmaf(a[i], bo[q][e], acc[i][q * 4 + e]);
            }
        }
        // stage tile kt+1 into the other buffer, one barrier pair per tile
        if (kt < 15) {
            __syncthreads();
#pragma unroll
            for (int q = 0; q < 4; ++q)
#pragma unroll
                for (int e = 0; e < 4; ++e)
                    At[cur ^ 1][sk16 + q * 4 + e][srow] = rx[q][e];
            __syncthreads();
        }
    }

#pragma unroll
    for (int i = 0; i < 4; ++i) {
        size_t base = (size_t)(RM + lane * 4 + i) * CC + CN;
#pragma unroll
        for (int q = 0; q < 4; ++q) {
            f32x4 o = {acc[i][q * 4], acc[i][q * 4 + 1],
                       acc[i][q * 4 + 2], acc[i][q * 4 + 3]};
            *(f32x4*)&H[base + q * 4] = o;
        }
    }
}

// ----------------------------- LIF (fp32, np-op-exact) ---------------------
// Spike byte: 0x3C (= high byte of fp16 1.0) or 0x00.
__global__ __launch_bounds__(256)
void lif_np(const float* __restrict__ H, unsigned char* __restrict__ S8) {
#pragma clang fp contract(off)
    int g = blockIdx.x * 256 + threadIdx.x;   // 0 .. BNC/4-1
    float v[4] = {0.f, 0.f, 0.f, 0.f};
#pragma unroll
    for (int t = 0; t < TT; ++t) {
        f32x4 h = *(const f32x4*)&H[(size_t)t * BNC + (size_t)g * 4];
        unsigned int pack = 0;
#pragma unroll
        for (int e = 0; e < 4; ++e) {
            float d  = h[e] - v[e];          // rounded sub (np: x - (v-0))
            float d2 = d * 0.5f;             // exact (np: /2.0)
            v[e] = v[e] + d2;                // rounded add
            bool sp = v[e] >= 1.0f;
            if (sp) { pack |= 0x3Cu << (8 * e); v[e] = 0.0f; }
        }
        *(unsigned int*)&S8[(size_t)t * BNC + (size_t)g * 4] = pack;
    }
}

// ---------------------------------------------------------------- GEMM2 ----
// O[m][p] = sum_o S[m][o] * W2[p][o]. fp16 MFMA; spikes exact in fp16.
__global__ __launch_bounds__(256)
void gemm2_f16(const unsigned char* __restrict__ S8, const float* __restrict__ W,
               float* __restrict__ O) {
    __shared__ _Float16 As[128][LDK], Bs[128][LDK];

    const int tid  = threadIdx.x;
    const int RM   = blockIdx.x * 128;
    const int CN   = blockIdx.y * 128;
    const int lane = tid & 63;
    const int wv   = tid >> 6;
    const int wr   = (wv >> 1) * 64;
    const int wc   = (wv & 1) * 64;
    const int r15  = lane & 15;
    const int kg   = lane >> 4;

    f32x4 acc[4][4] = {};

    for (int k0 = 0; k0 < CC; k0 += 32) {
        __syncthreads();
#pragma unroll
        for (int j = 0; j < 2; ++j) {
            int id  = tid + 256 * j;
            int row = id >> 2;
            int c8  = (id & 3) * 8;
            unsigned long long v =
                *(const unsigned long long*)&S8[(size_t)(RM + row) * CC + k0 + c8];
            ushort8 u;
#pragma unroll
            for (int e = 0; e < 8; ++e)
                u[e] = (unsigned short)(((v >> (8 * e)) & 0xFFull) << 8);
            *(ushort8*)&As[row][c8] = u;
        }
#pragma unroll
        for (int j = 0; j < 4; ++j) {
            int id  = tid + 256 * j;
            int row = id >> 3;
            int c4  = (id & 7) * 4;
            f32x4 v = *(const f32x4*)&W[(size_t)(CN + row) * CC + k0 + c4];
            half4v hv;
#pragma unroll
            for (int e = 0; e < 4; ++e) hv[e] = (_Float16)v[e];
            *(half4v*)&Bs[row][c4] = hv;
        }
        __syncthreads();

        half8 a[4], b[4];
#pragma unroll
        for (int i = 0; i < 4; ++i) {
            a[i] = *(const half8*)&As[wr + i * 16 + r15][kg * 8];
            b[i] = *(const half8*)&Bs[wc + i * 16 + r15][kg * 8];
        }
#pragma unroll
        for (int i = 0; i < 4; ++i)
#pragma unroll
            for (int j = 0; j < 4; ++j)
                acc[i][j] = __builtin_amdgcn_mfma_f32_16x16x32_f16(a[i], b[j], acc[i][j], 0, 0, 0);
    }

#pragma unroll
    for (int i = 0; i < 4; ++i)
#pragma unroll
        for (int j = 0; j < 4; ++j)
#pragma unroll
            for (int r = 0; r < 4; ++r) {
                int gm = RM + wr + i * 16 + kg * 4 + r;
                int gn = CN + wc + j * 16 + r15;
                O[(size_t)gm * CC + gn] = acc[i][j][r];
            }
}

// -------------------------------------------------------------- launch -----
extern "C" void kernel_launch(void* const* d_in, const int* in_sizes, int n_in,
                              void* d_out, int out_size, void* d_ws, size_t ws_size,
                              hipStream_t stream) {
    const float* x  = (const float*)d_in[0];
    const float* W1 = (const float*)d_in[1];
    const float* W2 = (const float*)d_in[2];
    float* out = (float*)d_out;

    float*         h  = out;                                   // fp32 h in d_out
    unsigned char* s8 = (unsigned char*)d_ws;                  // spikes, 16 MB
    float*         wt = (float*)((char*)d_ws + (size_t)BNC);   // Wt, 1 MB @ +16MB

    dim3 gt(CC / 64, CC / 64);       // (8, 8)
    transpose_w<<<gt, 256, 0, stream>>>(W1, wt);

    dim3 g1(MTOT / 256, CC / 128);   // (128, 4) = 512 blocks = 2/CU
    gemm1_vmem<<<g1, 512, 0, stream>>>(x, wt, h);

    lif_np<<<BNC / 4 / 256, 256, 0, stream>>>(h, s8);

    dim3 g2(MTOT / 128, CC / 128);   // (256, 4)
    gemm2_f16<<<g2, 256, 0, stream>>>(s8, W2, out);
}

// Round 15
// 349.110 us; speedup vs baseline: 15.4069x; 15.4069x over previous
//
#include <hip/hip_runtime.h>

// SpikeFFN: out = spike(LIF(x @ W1^T)) @ W2^T ; T=4 B=8 N=1024 C=512, fp32.
//
// HARD CONSTRAINT (r8): GEMM1 = single full-K ascending serial FMA chain per
// output in fp32 (np reference arithmetic); v_fma_f32 == CPU vfmadd.
// Tiling/load order free; per-output chain order is not.
//
// r13: B via SMEM (s_load) -> OOO returns share lgkm with DS -> per-k full
// drains, VALUBusy 66%, 197us. r14: B via VMEM but 16-col panel + tight
// launch_bounds -> acc spilled to scratch (VGPR_Count 64, FETCH 5.9GB, 2.4%
// VALU) -> 5368us. r15: VMEM-B with 8-col wave panel: acc[4][8]=32 regs,
// total ~90 VGPR (fits); launch_bounds(512,2) so the allocator has headroom;
// be/bo 1-k-deep register pipeline under 32 FMAs; counted vmcnt waits; DS
// (A reads) alone on lgkm. Wt padded with a 513th row so gk+1 prefetch is
// unclamped. X re-reads (8 col panels) are L3-absorbed.

typedef _Float16 half8  __attribute__((ext_vector_type(8)));
typedef _Float16 half4v __attribute__((ext_vector_type(4)));
typedef float    f32x4  __attribute__((ext_vector_type(4)));
typedef unsigned short ushort8 __attribute__((ext_vector_type(8)));

constexpr int TT   = 4;
constexpr int BB   = 8;
constexpr int NN   = 1024;
constexpr int CC   = 512;                 // Cin == Cout
constexpr int MROW = BB * NN;             // 8192 rows per timestep
constexpr int MTOT = TT * MROW;           // 32768 rows total
constexpr int BNC  = MROW * CC;           // per-timestep elems
constexpr int LDK  = 40;                  // fp16 LDS stride (gemm2)
constexpr int LTA  = 260;                 // fp32 LDS row stride (256+4 pad)

// --------------------------- W1 -> Wt[k][o] transpose ----------------------
__global__ __launch_bounds__(256)
void transpose_w(const float* __restrict__ W, float* __restrict__ Wt) {
    __shared__ float T[64][65];
    const int tid = threadIdx.x;
    const int bo  = blockIdx.x * 64;   // o tile
    const int bk  = blockIdx.y * 64;   // k tile
#pragma unroll
    for (int j = 0; j < 16; ++j) {
        int id = tid + 256 * j;
        int r = id >> 6, c = id & 63;              // r: o, c: k
        T[r][c] = W[(size_t)(bo + r) * CC + bk + c];
    }
    __syncthreads();
#pragma unroll
    for (int j = 0; j < 16; ++j) {
        int id = tid + 256 * j;
        int r = id >> 6, c = id & 63;              // r: k, c: o
        Wt[(size_t)(bk + r) * CC + bo + c] = T[c][r];
    }
}

// ---------- GEMM1: single full-K ascending serial FMA chain (fp32) ---------
// 256x64 block tile, 512 threads (8 waves x 8 cols), 4x8 outputs/thread.
// A in dbuf LDS (contiguous b128 lane reads, lgkm = DS only);
// B from Wt via VMEM broadcast loads, be/bo register pipeline (vmcnt waits).
__global__ __launch_bounds__(512, 2)
void gemm1_v15(const float* __restrict__ X, const float* __restrict__ Wt,
               float* __restrict__ H) {
#pragma clang fp contract(off)
    __shared__ float At[2][32][LTA];   // 66.5 KB

    const int tid  = threadIdx.x;
    const int lane = tid & 63;
    const int wid  = tid >> 6;                    // 0..7
    const int RM   = blockIdx.x * 256;
    const int CN   = blockIdx.y * 64 + wid * 8;   // wave col base
    const float* wcol = Wt + CN;                  // Wt[gk][CN..CN+7]

    const int srow = tid >> 1;           // staging row 0..255
    const int sk16 = (tid & 1) * 16;     // staging k base (0 or 16)

    float acc[4][8] = {};                // ONE accumulator per output
    f32x4 rx[4];                         // A staging prefetch
    f32x4 bc0, bc1, bn0, bn1;            // B current / next k registers

    // prologue: stage A tile 0; preload B row gk=0
#pragma unroll
    for (int q = 0; q < 4; ++q)
        rx[q] = *(const f32x4*)&X[(size_t)(RM + srow) * CC + sk16 + q * 4];
#pragma unroll
    for (int q = 0; q < 4; ++q)
#pragma unroll
        for (int e = 0; e < 4; ++e)
            At[0][sk16 + q * 4 + e][srow] = rx[q][e];
    bc0 = *(const f32x4*)&wcol[0];
    bc1 = *(const f32x4*)&wcol[4];
    __syncthreads();

    for (int kt = 0; kt < 16; ++kt) {
        const int cur = kt & 1;
        // issue A loads for tile kt+1 (land under this tile's FMAs)
        if (kt < 15) {
            int kk = (kt + 1) * 32;
#pragma unroll
            for (int q = 0; q < 4; ++q)
                rx[q] = *(const f32x4*)&X[(size_t)(RM + srow) * CC + kk + sk16 + q * 4];
        }
        // FMA phase: strict ascending k; B prefetched one k ahead (row gk+1;
        // gk=511 prefetches the garbage 513th row, discarded unused).
#pragma unroll 8
        for (int k = 0; k < 32; ++k) {
            const int gk = kt * 32 + k;
            bn0 = *(const f32x4*)&wcol[(size_t)(gk + 1) * CC];
            bn1 = *(const f32x4*)&wcol[(size_t)(gk + 1) * CC + 4];
            f32x4 a = *(const f32x4*)&At[cur][k][lane * 4];
#pragma unroll
            for (int i = 0; i < 4; ++i)
#pragma unroll
                for (int e = 0; e < 4; ++e) {
                    acc[i][e]     = __builtin_fmaf(a[i], bc0[e], acc[i][e]);
                    acc[i][4 + e] = __builtin_fmaf(a[i], bc1[e], acc[i][4 + e]);
                }
            bc0 = bn0;
            bc1 = bn1;
        }
        // stage tile kt+1, one barrier pair per tile
        if (kt < 15) {
            __syncthreads();
#pragma unroll
            for (int q = 0; q < 4; ++q)
#pragma unroll
                for (int e = 0; e < 4; ++e)
                    At[cur ^ 1][sk16 + q * 4 + e][srow] = rx[q][e];
            __syncthreads();
        }
    }

#pragma unroll
    for (int i = 0; i < 4; ++i) {
        size_t base = (size_t)(RM + lane * 4 + i) * CC + CN;
        f32x4 o0 = {acc[i][0], acc[i][1], acc[i][2], acc[i][3]};
        f32x4 o1 = {acc[i][4], acc[i][5], acc[i][6], acc[i][7]};
        *(f32x4*)&H[base]     = o0;
        *(f32x4*)&H[base + 4] = o1;
    }
}

// ----------------------------- LIF (fp32, np-op-exact) ---------------------
// Spike byte: 0x3C (= high byte of fp16 1.0) or 0x00.
__global__ __launch_bounds__(256)
void lif_np(const float* __restrict__ H, unsigned char* __restrict__ S8) {
#pragma clang fp contract(off)
    int g = blockIdx.x * 256 + threadIdx.x;   // 0 .. BNC/4-1
    float v[4] = {0.f, 0.f, 0.f, 0.f};
#pragma unroll
    for (int t = 0; t < TT; ++t) {
        f32x4 h = *(const f32x4*)&H[(size_t)t * BNC + (size_t)g * 4];
        unsigned int pack = 0;
#pragma unroll
        for (int e = 0; e < 4; ++e) {
            float d  = h[e] - v[e];          // rounded sub (np: x - (v-0))
            float d2 = d * 0.5f;             // exact (np: /2.0)
            v[e] = v[e] + d2;                // rounded add
            bool sp = v[e] >= 1.0f;
            if (sp) { pack |= 0x3Cu << (8 * e); v[e] = 0.0f; }
        }
        *(unsigned int*)&S8[(size_t)t * BNC + (size_t)g * 4] = pack;
    }
}

// ---------------------------------------------------------------- GEMM2 ----
// O[m][p] = sum_o S[m][o] * W2[p][o]. fp16 MFMA; spikes exact in fp16.
__global__ __launch_bounds__(256)
void gemm2_f16(const unsigned char* __restrict__ S8, const float* __restrict__ W,
               float* __restrict__ O) {
    __shared__ _Float16 As[128][LDK], Bs[128][LDK];

    const int tid  = threadIdx.x;
    const int RM   = blockIdx.x * 128;
    const int CN   = blockIdx.y * 128;
    const int lane = tid & 63;
    const int wv   = tid >> 6;
    const int wr   = (wv >> 1) * 64;
    const int wc   = (wv & 1) * 64;
    const int r15  = lane & 15;
    const int kg   = lane >> 4;

    f32x4 acc[4][4] = {};

    for (int k0 = 0; k0 < CC; k0 += 32) {
        __syncthreads();
#pragma unroll
        for (int j = 0; j < 2; ++j) {
            int id  = tid + 256 * j;
            int row = id >> 2;
            int c8  = (id & 3) * 8;
            unsigned long long v =
                *(const unsigned long long*)&S8[(size_t)(RM + row) * CC + k0 + c8];
            ushort8 u;
#pragma unroll
            for (int e = 0; e < 8; ++e)
                u[e] = (unsigned short)(((v >> (8 * e)) & 0xFFull) << 8);
            *(ushort8*)&As[row][c8] = u;
        }
#pragma unroll
        for (int j = 0; j < 4; ++j) {
            int id  = tid + 256 * j;
            int row = id >> 3;
            int c4  = (id & 7) * 4;
            f32x4 v = *(const f32x4*)&W[(size_t)(CN + row) * CC + k0 + c4];
            half4v hv;
#pragma unroll
            for (int e = 0; e < 4; ++e) hv[e] = (_Float16)v[e];
            *(half4v*)&Bs[row][c4] = hv;
        }
        __syncthreads();

        half8 a[4], b[4];
#pragma unroll
        for (int i = 0; i < 4; ++i) {
            a[i] = *(const half8*)&As[wr + i * 16 + r15][kg * 8];
            b[i] = *(const half8*)&Bs[wc + i * 16 + r15][kg * 8];
        }
#pragma unroll
        for (int i = 0; i < 4; ++i)
#pragma unroll
            for (int j = 0; j < 4; ++j)
                acc[i][j] = __builtin_amdgcn_mfma_f32_16x16x32_f16(a[i], b[j], acc[i][j], 0, 0, 0);
    }

#pragma unroll
    for (int i = 0; i < 4; ++i)
#pragma unroll
        for (int j = 0; j < 4; ++j)
#pragma unroll
            for (int r = 0; r < 4; ++r) {
                int gm = RM + wr + i * 16 + kg * 4 + r;
                int gn = CN + wc + j * 16 + r15;
                O[(size_t)gm * CC + gn] = acc[i][j][r];
            }
}

// -------------------------------------------------------------- launch -----
extern "C" void kernel_launch(void* const* d_in, const int* in_sizes, int n_in,
                              void* d_out, int out_size, void* d_ws, size_t ws_size,
                              hipStream_t stream) {
    const float* x  = (const float*)d_in[0];
    const float* W1 = (const float*)d_in[1];
    const float* W2 = (const float*)d_in[2];
    float* out = (float*)d_out;

    float*         h  = out;                                   // fp32 h in d_out
    unsigned char* s8 = (unsigned char*)d_ws;                  // spikes, 16 MB
    float*         wt = (float*)((char*)d_ws + (size_t)BNC);   // Wt, 513 rows

    dim3 gt(CC / 64, CC / 64);       // (8, 8)
    transpose_w<<<gt, 256, 0, stream>>>(W1, wt);

    dim3 g1(MTOT / 256, CC / 64);    // (128, 8) = 1024 blocks
    gemm1_v15<<<g1, 512, 0, stream>>>(x, wt, h);

    lif_np<<<BNC / 4 / 256, 256, 0, stream>>>(h, s8);

    dim3 g2(MTOT / 128, CC / 128);   // (256, 4)
    gemm2_f16<<<g2, 256, 0, stream>>>(s8, W2, out);
}